// Round 5
// baseline (93.710 us; speedup 1.0000x reference)
//
#include <hip/hip_runtime.h>

// MinibatchDiscrimination: B=512, IN=512, OUT=64, KD=8 (fp32 in/out)
// out[i, 0:512] = x[i, :]
// out[i, 512+o] = sum_j exp(-sum_k |M[i,o,k] - M[j,o,k]|),  M = x @ T
//
// R5: ONE kernel, ZERO d_ws usage (no dependency on the harness's 256 MiB
// poison fill; no inter-kernel boundary).
// Grid 256 = (o in [0,64)) x (ic in [0,4)), 512 threads = 8 waves.
// Phase 1: block computes its own o-slice M[:,o,:] (512x8) via MFMA
//          16x16x32 bf16 into LDS. B = T[:, o*8..o*8+8) staged transposed
//          as bf16 (rows 8..15 of the fragment zeroed); A = x fp32 read
//          direct from global (L2-resident), packed to bf16 in-reg.
//          Wave w owns i-rows [w*64, w*64+64) -> x read exactly once/block.
// Phase 2: pairs for i in [ic*128, ic*128+128), all 512 j from the LDS
//          slice (wave-uniform reads -> broadcast). Cross-wave LDS
//          reduction -> exclusive plain store (no atomics, no pre-zero).
// Side job: x -> out[:, 0:512) copy folded into phase 1.

#define B_    512
#define IN_   512
#define OUT_  64
#define KD_   8
#define ROW_  576
#define ROW4_ 144
#define TSTR  520   // Tt row stride (ushorts): 16B-aligned rows, low conflicts

typedef short short8 __attribute__((ext_vector_type(8)));
typedef float f32x4  __attribute__((ext_vector_type(4)));

__device__ __forceinline__ unsigned short f2bf(float f) {
    return (unsigned short)((__float_as_uint(f) + 0x8000u) >> 16);
}
__device__ __forceinline__ unsigned pack_bf2(float lo, float hi) {
    unsigned a = (__float_as_uint(lo) + 0x8000u) >> 16;
    unsigned b = (__float_as_uint(hi) + 0x8000u) & 0xFFFF0000u;
    return a | b;
}

__global__ __launch_bounds__(512)
void fused_kernel(const float* __restrict__ x, const float* __restrict__ T,
                  float* __restrict__ out) {
    __shared__ unsigned short Tt[16][TSTR];  // 16.3 KB; rows 8..15 stay zero
    __shared__ float s[B_][KD_];             // 16 KB: this block's o-slice
    __shared__ float s2[8][128];             // 4 KB: per-wave pair partials
    int t  = threadIdx.x;
    int bx = blockIdx.x;
    int o  = bx >> 2;
    int ic = bx & 3;

    // zero the unused B-fragment rows (n = 8..15)
    unsigned* tz = (unsigned*)&Tt[8][0];
    for (int idx = t; idx < (8 * TSTR) / 2; idx += 512) tz[idx] = 0;

    // stage Tt[c][k] = bf16(T[k, o*8+c]) : c in [0,8), k in [0,512)
    {
        int c  = t & 7;
        int kb = t >> 3;                     // 0..63
        #pragma unroll
        for (int p = 0; p < 8; ++p) {
            int k = kb + p * 64;
            Tt[c][k] = f2bf(T[k * 512 + o * 8 + c]);
        }
    }

    // side job: this block's share of the x -> out copy (256 float4)
    if (t < 256) {
        int v  = bx * 256 + t;               // [0, 65536)
        int i  = v >> 7;
        int c4 = v & 127;
        ((float4*)out)[i * ROW4_ + c4] = ((const float4*)x)[v];
    }
    __syncthreads();

    // ---------------- phase 1: M[:, o, :] via MFMA --------------------------
    int lane = t & 63, w = t >> 6;
    int r = lane & 15, q = lane >> 4;
    {
        f32x4 acc[4] = {{0,0,0,0}, {0,0,0,0}, {0,0,0,0}, {0,0,0,0}};
        const float* pa = x + (w * 64 + r) * 512 + q * 8;   // wave's row block
        #pragma unroll
        for (int kt = 0; kt < 16; ++kt) {
            short8 Bv = *(const short8*)&Tt[r][q * 8 + kt * 32];
            #pragma unroll
            for (int it = 0; it < 4; ++it) {
                const float* p = pa + it * 16 * 512 + kt * 32;
                float4 f0 = *(const float4*)p;
                float4 f1 = *(const float4*)(p + 4);
                union { unsigned u[4]; short8 v; } A;
                A.u[0] = pack_bf2(f0.x, f0.y);
                A.u[1] = pack_bf2(f0.z, f0.w);
                A.u[2] = pack_bf2(f1.x, f1.y);
                A.u[3] = pack_bf2(f1.z, f1.w);
                acc[it] = __builtin_amdgcn_mfma_f32_16x16x32_bf16(A.v, Bv, acc[it], 0, 0, 0);
            }
        }
        // C/D map: value rr of lane -> row q*4+rr, col r; cols 8..15 are junk
        if (r < 8) {
            #pragma unroll
            for (int it = 0; it < 4; ++it) {
                int i0 = w * 64 + it * 16;
                #pragma unroll
                for (int rr = 0; rr < 4; ++rr)
                    s[i0 + q * 4 + rr][r] = acc[it][rr];
            }
        }
    }
    __syncthreads();

    // ---------------- phase 2: all-pairs L1 + exp ---------------------------
    float mi[2][KD_];
    #pragma unroll
    for (int ii = 0; ii < 2; ++ii) {
        int i = ic * 128 + lane + ii * 64;
        float4 lo = *(const float4*)&s[i][0];
        float4 hi = *(const float4*)&s[i][4];
        mi[ii][0] = lo.x; mi[ii][1] = lo.y; mi[ii][2] = lo.z; mi[ii][3] = lo.w;
        mi[ii][4] = hi.x; mi[ii][5] = hi.y; mi[ii][6] = hi.z; mi[ii][7] = hi.w;
    }

    float acc0 = 0.f, acc1 = 0.f;
    const float* sj = &s[w * 64][0];         // wave-uniform -> LDS broadcast
    #pragma unroll 4
    for (int jj = 0; jj < 64; ++jj) {
        float v0 = sj[0], v1 = sj[1], v2 = sj[2], v3 = sj[3];
        float v4 = sj[4], v5 = sj[5], v6 = sj[6], v7 = sj[7];
        sj += KD_;
        float d0 = fabsf(mi[0][0] - v0) + fabsf(mi[0][1] - v1)
                 + fabsf(mi[0][2] - v2) + fabsf(mi[0][3] - v3)
                 + fabsf(mi[0][4] - v4) + fabsf(mi[0][5] - v5)
                 + fabsf(mi[0][6] - v6) + fabsf(mi[0][7] - v7);
        float d1 = fabsf(mi[1][0] - v0) + fabsf(mi[1][1] - v1)
                 + fabsf(mi[1][2] - v2) + fabsf(mi[1][3] - v3)
                 + fabsf(mi[1][4] - v4) + fabsf(mi[1][5] - v5)
                 + fabsf(mi[1][6] - v6) + fabsf(mi[1][7] - v7);
        acc0 += __expf(-d0);
        acc1 += __expf(-d1);
    }
    s2[w][lane]      = acc0;
    s2[w][lane + 64] = acc1;
    __syncthreads();

    // exclusive final store: this block owns (o, i) for i in [ic*128, +128)
    if (t < 128) {
        float v = 0.f;
        #pragma unroll
        for (int ww = 0; ww < 8; ++ww) v += s2[ww][t];
        out[(ic * 128 + t) * ROW_ + IN_ + o] = v;
    }
}

extern "C" void kernel_launch(void* const* d_in, const int* in_sizes, int n_in,
                              void* d_out, int out_size, void* d_ws, size_t ws_size,
                              hipStream_t stream) {
    const float* x = (const float*)d_in[0];   // [512, 512]
    const float* T = (const float*)d_in[1];   // [512, 64, 8]
    float* out = (float*)d_out;               // [512, 576]
    (void)d_ws; (void)ws_size;                // deliberately unused

    fused_kernel<<<256, 512, 0, stream>>>(x, T, out);
}